// Round 1
// baseline (111.715 us; speedup 1.0000x reference)
//
#include <hip/hip_runtime.h>
#include <hip/hip_bf16.h>

#define N_ROWS 4096
#define TWO_N  8192
#define ZDIM   256
#define INV_T  (1.0f/0.07f)
// exp((s-1)/T) = exp2((s-1) * INV_T * log2(e))
#define EXP_SCALE (INV_T * 1.44269504088896340736f)

typedef __attribute__((ext_vector_type(8))) short bf16x8;   // 8 bf16 in 4 VGPRs
typedef __attribute__((ext_vector_type(4))) float f32x4;

__device__ __forceinline__ void async_load16(const void* g, void* lds_uniform_base) {
  // HW computes LDS dest = (wave-uniform base) + lane*16; pass base WITHOUT lane term.
  __builtin_amdgcn_global_load_lds(
      (const __attribute__((address_space(1))) void*)g,
      (__attribute__((address_space(3))) void*)lds_uniform_base, 16, 0, 0);
}

// ---------------- Kernel A: normalize rows, emit bf16 reps, fp32 pos, zero rowsum --------
__global__ __launch_bounds__(256) void normalize_kernel(
    const float* __restrict__ z1, const float* __restrict__ z2,
    __hip_bfloat16* __restrict__ reps, float* __restrict__ pos,
    float* __restrict__ rowsum) {
  const int b = blockIdx.x;
  const int t = threadIdx.x;
  const float x1 = z1[b * ZDIM + t];
  const float x2 = z2[b * ZDIM + t];
  float s1 = x1 * x1, s2 = x2 * x2, s3 = x1 * x2;
  #pragma unroll
  for (int m = 1; m < 64; m <<= 1) {
    s1 += __shfl_xor(s1, m, 64);
    s2 += __shfl_xor(s2, m, 64);
    s3 += __shfl_xor(s3, m, 64);
  }
  __shared__ float red[3][4];
  const int w = t >> 6, l = t & 63;
  if (l == 0) { red[0][w] = s1; red[1][w] = s2; red[2][w] = s3; }
  __syncthreads();
  const float n1 = red[0][0] + red[0][1] + red[0][2] + red[0][3];
  const float n2 = red[1][0] + red[1][1] + red[1][2] + red[1][3];
  const float dt = red[2][0] + red[2][1] + red[2][2] + red[2][3];
  const float inv1 = 1.0f / fmaxf(sqrtf(n1), 1e-12f);
  const float inv2 = 1.0f / fmaxf(sqrtf(n2), 1e-12f);
  reps[b * ZDIM + t]            = __float2bfloat16(x1 * inv1);
  reps[(b + N_ROWS) * ZDIM + t] = __float2bfloat16(x2 * inv2);
  if (t == 0) {
    pos[b] = dt * inv1 * inv2;
    rowsum[b] = 0.0f;
    rowsum[b + N_ROWS] = 0.0f;
  }
}

// ---------------- Kernel B: flash row-sums of exp((sim-1)/T), diag masked ----------------
// Grid: (64 row-blocks, 8 col-chunks). Block: 256 thr = 4 waves in 2x2 over 128x128 tile.
// LDS: A tile 128x256 bf16 (64KB, staged once) + B tile 128x64 bf16 (16KB per K-chunk)
//      = 80KB -> 2 blocks/CU; 512 blocks = exactly 2/CU, fully resident.
__global__ __launch_bounds__(256, 2) void simsum_kernel(
    const __hip_bfloat16* __restrict__ reps, float* __restrict__ rowsum) {
  __shared__ __align__(16) __hip_bfloat16 Alds[128 * 256];  // 64 KB
  __shared__ __align__(16) __hip_bfloat16 Blds[128 * 64];   // 16 KB

  const int tid  = threadIdx.x;
  const int lane = tid & 63;
  const int wave = tid >> 6;
  const int wm = wave >> 1, wn = wave & 1;   // 2x2 wave grid
  const int quad = lane >> 4;                // 0..3
  const int l16  = lane & 15;
  const int rowBase  = blockIdx.x * 128;
  const int colChunk = blockIdx.y * 1024;
  const char* gbase = (const char*)reps;

  // Stage A tile: rows [rowBase, rowBase+128), full K=256.
  // LDS chunk c (16B) holds global chunk (c & ~7) | ((c ^ row)&7)  [XOR swizzle -> conflict-free ds_read_b128]
  #pragma unroll
  for (int p = 0; p < 16; ++p) {
    const int cbase = p * 256 + (wave << 6);
    const int c = cbase + lane;
    const int row = c >> 5;                 // 32 chunks per 512B row
    const int ch = (c & 31) ^ (row & 7);    // XOR low 3 bits only
    const int gofs = ((rowBase + row) * ZDIM + ch * 8) * 2;
    async_load16(gbase + gofs, (char*)Alds + cbase * 16);
  }

  float rowpart[16];
  #pragma unroll
  for (int i = 0; i < 16; ++i) rowpart[i] = 0.0f;

  const f32x4 zero4 = {0.0f, 0.0f, 0.0f, 0.0f};

  for (int ct = 0; ct < 8; ++ct) {
    const int colBase = colChunk + ct * 128;
    f32x4 acc[4][4];
    #pragma unroll
    for (int mi = 0; mi < 4; ++mi)
      #pragma unroll
      for (int ni = 0; ni < 4; ++ni) acc[mi][ni] = zero4;

    for (int kc = 0; kc < 4; ++kc) {
      // stage B chunk: rows [colBase, +128), k in [kc*64, +64)
      #pragma unroll
      for (int p = 0; p < 4; ++p) {
        const int cbase = p * 256 + (wave << 6);
        const int c = cbase + lane;
        const int row = c >> 3;               // 8 chunks per 128B row
        const int ch = (c & 7) ^ (row & 7);
        const int gofs = ((colBase + row) * ZDIM + kc * 64 + ch * 8) * 2;
        async_load16(gbase + gofs, (char*)Blds + cbase * 16);
      }
      __syncthreads();   // drains global_load_lds (vmcnt(0) before s_barrier)

      #pragma unroll
      for (int kk2 = 0; kk2 < 2; ++kk2) {
        bf16x8 afrag[4], bfrag[4];
        #pragma unroll
        for (int mi = 0; mi < 4; ++mi) {
          const int m = wm * 64 + mi * 16 + l16;
          const int ch = kc * 8 + kk2 * 4 + quad;           // chunk in [0,32)
          afrag[mi] = *(const bf16x8*)((const char*)Alds + (m * 32 + (ch ^ (m & 7))) * 16);
        }
        #pragma unroll
        for (int ni = 0; ni < 4; ++ni) {
          const int n = wn * 64 + ni * 16 + l16;
          const int ch = kk2 * 4 + quad;                    // chunk in [0,8)
          bfrag[ni] = *(const bf16x8*)((const char*)Blds + (n * 8 + (ch ^ (n & 7))) * 16);
        }
        #pragma unroll
        for (int mi = 0; mi < 4; ++mi)
          #pragma unroll
          for (int ni = 0; ni < 4; ++ni)
            acc[mi][ni] = __builtin_amdgcn_mfma_f32_16x16x32_bf16(
                afrag[mi], bfrag[ni], acc[mi][ni], 0, 0, 0);
      }
      __syncthreads();   // all waves done with Blds before restage
    }

    // Epilogue: exp((s-1)/T) with diagonal mask, accumulate per-lane row partials.
    // C/D layout: col = lane&15, row = quad*4 + reg (robust to transpose: sim symmetric)
    #pragma unroll
    for (int mi = 0; mi < 4; ++mi) {
      #pragma unroll
      for (int r = 0; r < 4; ++r) {
        const int grow = rowBase + wm * 64 + mi * 16 + quad * 4 + r;
        float s = 0.0f;
        #pragma unroll
        for (int ni = 0; ni < 4; ++ni) {
          const int gcol = colBase + wn * 64 + ni * 16 + l16;
          const float v = acc[mi][ni][r];
          const float e = exp2f((v - 1.0f) * EXP_SCALE);
          if (grow != gcol) s += e;
        }
        rowpart[mi * 4 + r] += s;
      }
    }
  }

  // Reduce across the 16 lanes sharing each row (xor over low 4 lane bits)
  #pragma unroll
  for (int i = 0; i < 16; ++i) {
    float v = rowpart[i];
    v += __shfl_xor(v, 1, 64);
    v += __shfl_xor(v, 2, 64);
    v += __shfl_xor(v, 4, 64);
    v += __shfl_xor(v, 8, 64);
    rowpart[i] = v;
  }
  if (l16 == 0) {
    #pragma unroll
    for (int mi = 0; mi < 4; ++mi)
      #pragma unroll
      for (int r = 0; r < 4; ++r)
        atomicAdd(&rowsum[rowBase + wm * 64 + mi * 16 + quad * 4 + r],
                  rowpart[mi * 4 + r]);
  }
}

// ---------------- Kernel C: loss = 1/T + mean(log rowsum) - mean_pos/T -------------------
__global__ __launch_bounds__(1024) void loss_kernel(
    const float* __restrict__ rowsum, const float* __restrict__ pos,
    float* __restrict__ out) {
  const int t = threadIdx.x;
  float slog = 0.0f;
  for (int i = t; i < TWO_N; i += 1024) slog += logf(rowsum[i]);
  float spos = 0.0f;
  for (int i = t; i < N_ROWS; i += 1024) spos += pos[i];
  #pragma unroll
  for (int m = 1; m < 64; m <<= 1) {
    slog += __shfl_xor(slog, m, 64);
    spos += __shfl_xor(spos, m, 64);
  }
  __shared__ float rl[16], rp[16];
  const int w = t >> 6, l = t & 63;
  if (l == 0) { rl[w] = slog; rp[w] = spos; }
  __syncthreads();
  if (t == 0) {
    float tl = 0.0f, tp = 0.0f;
    #pragma unroll
    for (int i = 0; i < 16; ++i) { tl += rl[i]; tp += rp[i]; }
    // loss = 1/T + (1/2N) * sum(log rowsum_i) - (1/T) * (2*sum(pos_b)) / 2N
    out[0] = INV_T + tl / (float)TWO_N - tp * INV_T / (float)N_ROWS;
  }
}

extern "C" void kernel_launch(void* const* d_in, const int* in_sizes, int n_in,
                              void* d_out, int out_size, void* d_ws, size_t ws_size,
                              hipStream_t stream) {
  const float* z1 = (const float*)d_in[0];
  const float* z2 = (const float*)d_in[1];
  __hip_bfloat16* reps = (__hip_bfloat16*)d_ws;                       // 8192*256*2 = 4 MB
  float* rowsum = (float*)((char*)d_ws + (size_t)TWO_N * ZDIM * 2);   // 32 KB
  float* pos = rowsum + TWO_N;                                        // 16 KB

  normalize_kernel<<<N_ROWS, 256, 0, stream>>>(z1, z2, reps, pos, rowsum);
  simsum_kernel<<<dim3(64, 8), 256, 0, stream>>>(reps, rowsum);
  loss_kernel<<<1, 1024, 0, stream>>>(rowsum, pos, (float*)d_out);
}